// Round 13
// baseline (6331.531 us; speedup 1.0000x reference)
//
#include <hip/hip_runtime.h>

typedef __attribute__((ext_vector_type(8))) _Float16 f16x8;
typedef __attribute__((ext_vector_type(4))) _Float16 f16x4;
typedef __attribute__((ext_vector_type(4))) float f32x4;
typedef __attribute__((ext_vector_type(4))) unsigned int u32x4;
typedef __attribute__((ext_vector_type(2))) unsigned int u32x2;

#define B_SZ 64
#define T_SZ 512
#define I_SZ 512
#define H_SZ 1024
#define G4   4096
#define NBLK 256
#define HB   (B_SZ * H_SZ)   // u32 elements per hpair slot

// ---------- prep: transpose + gate-interleave weights ----------
// src: [R][1024] fp32 (gate q's U or V). dst: [4096][R] f16, dst[4*n+q][r] = src[r][n]
__global__ void trans_kernel(const float* __restrict__ src, _Float16* __restrict__ dst,
                             int R, int q) {
  __shared__ float tile[64][65];
  const int n0 = blockIdx.x * 64;
  const int r0 = blockIdx.y * 64;
  const int x = threadIdx.x & 63, y = threadIdx.x >> 6;
  #pragma unroll
  for (int it = 0; it < 16; ++it) {
    int r = y * 16 + it;
    tile[r][x] = src[(size_t)(r0 + r) * H_SZ + n0 + x];
  }
  __syncthreads();
  #pragma unroll
  for (int it = 0; it < 16; ++it) {
    int rn = y * 16 + it;
    dst[(size_t)(4 * (n0 + rn) + q) * R + r0 + x] = (_Float16)tile[x][rn];
  }
}

// ---------- prep: interleave bias ----------
__global__ void bias_kernel(const float* __restrict__ b0, const float* __restrict__ b1,
                            const float* __restrict__ b2, const float* __restrict__ b3,
                            float* __restrict__ dst) {
  int g = blockIdx.x * blockDim.x + threadIdx.x;
  if (g >= G4) return;
  int q = g & 3, n = g >> 2;
  const float* s = (q == 0) ? b0 : (q == 1) ? b1 : (q == 2) ? b2 : b3;
  dst[g] = s[n];
}

__device__ __forceinline__ float h2f(unsigned short u) {
  union { unsigned short s; _Float16 h; } c; c.s = u; return (float)c.h;
}
__device__ __forceinline__ unsigned short f2h(float f) {
  union { unsigned short s; _Float16 h; } c; c.h = (_Float16)f; return c.s;
}

// x prefetch: all 256 threads, 8x16B f32 chunks, linear source (coalesced)
__device__ __forceinline__ void x_issue(const float* x, int b0, int tid, int t, f32x4* xst) {
  #pragma unroll
  for (int j = 0; j < 8; ++j) {
    const int byteoff = j * 4096 + tid * 16;   // f32-slice byte offset
    const int row  = byteoff >> 11;            // 2048 B per f32 row
    const int colb = byteoff & 2047;
    const char* sp = (const char*)x + (((size_t)(b0 + row) * T_SZ + t) * I_SZ) * 4 + colb;
    asm volatile("global_load_dwordx4 %0, %1, off" : "=v"(xst[j]) : "v"(sp) : "memory");
  }
}
// cvt f32->f16 once at stage time; write 8B chunks, XOR-swizzled (16B granules)
__device__ __forceinline__ void x_write(char* xl, int tid, const f32x4* xst) {
  #pragma unroll
  for (int j = 0; j < 8; ++j) {
    const int byteoff = j * 4096 + tid * 16;
    const int row  = byteoff >> 11;
    const int colb = (byteoff & 2047) >> 1;    // f16 byte offset, 8B-aligned
    f16x4 v = { (_Float16)xst[j].x, (_Float16)xst[j].y,
                (_Float16)xst[j].z, (_Float16)xst[j].w };
    *(f16x4*)(xl + (row << 10) + (colb ^ ((row & 7) << 4))) = v;
  }
}

// ---------- persistent recurrence: tagged-word sync (flag-free) ----------
// h is published as u32 words (tag=t+1)<<16 | h_f16 into a 2-slot ring.
// A dword store is atomic -> each word self-describes readiness: no producer
// drain, no flags, no flag poll. The consumer's gather IS the poll (re-issue
// until all 64 tags match). 2 barriers/step. Ring safety: a producer reaches
// slot-s publish only after fully gathering slot s^1, which transitively
// requires every block to have finished reading slot s (tag-checked on top).
// Blocks/waves/fragment math identical to round 9 (verified).
__global__ __launch_bounds__(256, 1) void lstm_recur(
    const float* __restrict__ x,        // [B][T][I] fp32
    const _Float16* __restrict__ Ubt,   // [4096][512]  row 4n+q = U_q[:,n]
    const _Float16* __restrict__ Vt,    // [4096][1024] row 4n+q = V_q[:,n]
    const float* __restrict__ biasw,    // [4096] interleaved
    float* __restrict__ out,            // hidden_seq | h_T | c_T
    unsigned* __restrict__ hpair)       // [2][64][1024] u32 tagged-h ring
{
  __shared__ __align__(16) char hsh[32768];    // h slice [16][1024] f16, swizzled
  __shared__ __align__(16) char xlds[32768];   // x dbuf [2][16][512] f16, swizzled

  const int tid  = threadIdx.x;
  const int lane = tid & 63;
  const int wv   = tid >> 6;
  const int lc   = lane & 15;     // col-in-wave / A-row sel
  const int lk   = lane >> 4;     // k-group
  const int q    = lc & 3;        // gate id (0=i,1=f,2=g,3=o)
  const int p    = lc >> 2;       // quad id
  const int blk  = blockIdx.x;
  const int bgrp = blk & 3;       // batch chain (XCD pair)
  const int hgrp = blk >> 2;      // 0..63
  const int col0 = hgrp * 64 + wv * 16;
  const int b0   = bgrp * 16;
  const int sw   = (lc & 7) << 4; // read-side swizzle

  // ---- stationary weights: load once, pin via opaque asm ----
  f16x8 bU[16];
  f16x8 bV[32];
  {
    const _Float16* up = Ubt + (size_t)(col0 + lc) * I_SZ + lk * 8;
    #pragma unroll
    for (int ks = 0; ks < 16; ++ks) bU[ks] = *(const f16x8*)(up + ks * 32);
    const _Float16* vp = Vt + (size_t)(col0 + lc) * H_SZ + lk * 8;
    #pragma unroll
    for (int ks = 0; ks < 32; ++ks) bV[ks] = *(const f16x8*)(vp + ks * 32);
  }
  #pragma unroll
  for (int ks = 0; ks < 16; ++ks) asm volatile("" : "+v"(bU[ks]));
  #pragma unroll
  for (int ks = 0; ks < 32; ++ks) asm volatile("" : "+v"(bV[ks]));

  const float bias_v = biasw[col0 + lc];
  const int n_glob = hgrp * 16 + wv * 4 + p;
  const int cb     = hgrp * 16 + wv * 4;
  const size_t HO = (size_t)B_SZ * T_SZ * H_SZ;
  const size_t CO = HO + (size_t)B_SZ * H_SZ;

  float cst[4] = {0.f, 0.f, 0.f, 0.f};

  // gather geometry: thread owns 1 row x 64 cols (256B contiguous) -> its
  // words come from only 4 producer blocks (partial-progress detection)
  const int grow = tid >> 4;            // 0..15 (batch row)
  const int gcol = (tid & 15) * 64;     // u32 col base
  const int gcb  = (tid & 15) * 128;    // byte base in hsh row
  const int gsw  = (grow & 7) << 4;

  // ---- prime x(0) into xlds[0] ----
  f32x4 xst[8];
  x_issue(x, b0, tid, 0, xst);
  asm volatile("s_waitcnt vmcnt(0)" ::: "memory");
  __builtin_amdgcn_sched_barrier(0);
  x_write(xlds, tid, xst);
  asm volatile("s_waitcnt lgkmcnt(0)" ::: "memory");
  __builtin_amdgcn_s_barrier();
  __builtin_amdgcn_sched_barrier(0);

#define XPROJ(ks) { \
    const f16x8 a_ = *(const f16x8*)(xl_cur + (lc << 10) + ((((ks) * 64) + lk * 16) ^ sw)); \
    acc[(ks) & 3] = __builtin_amdgcn_mfma_f32_16x16x32_f16(a_, bU[(ks)], acc[(ks) & 3], 0, 0, 0); }
#define HPROJ(ks) { \
    const f16x8 hv = *(const f16x8*)(hsh + (lc << 11) + (((lk * 16) + (ks) * 64) ^ sw)); \
    acc[(ks) & 3] = __builtin_amdgcn_mfma_f32_16x16x32_f16(hv, bV[(ks)], acc[(ks) & 3], 0, 0, 0); }
#define GLOAD(j) asm volatile("global_load_dwordx4 %0, %1, off sc0 sc1" \
    : "=v"(g[(j)]) : "v"(gp + (j) * 4) : "memory");

  for (int t = 0; t < T_SZ; ++t) {
    char* xl_cur = xlds + (size_t)(t & 1) * 16384;
    char* xl_nxt = xlds + (size_t)((t + 1) & 1) * 16384;

    f32x4 acc[4];
    acc[0] = f32x4{bias_v, bias_v, bias_v, bias_v};
    acc[1] = f32x4{0.f, 0.f, 0.f, 0.f};
    acc[2] = f32x4{0.f, 0.f, 0.f, 0.f};
    acc[3] = f32x4{0.f, 0.f, 0.f, 0.f};

    // ---- 1: issue first gather sample of tagged h(t) ----
    const unsigned* gp = hpair + (size_t)(t & 1) * HB + (size_t)(b0 + grow) * H_SZ + gcol;
    u32x4 g[16];
    #pragma unroll
    for (int j = 0; j < 16; ++j) GLOAD(j);

    // ---- 2: x projection (overlaps gather flight; off the serial chain) ----
    #pragma unroll
    for (int ks = 0; ks < 16; ++ks) XPROJ(ks);

    // ---- 3: poll: check tags; re-issue until all 64 match ----
    {
      const unsigned texp = (unsigned)t & 0xffffu;
      unsigned bad;
      for (;;) {
        asm volatile("s_waitcnt vmcnt(0)" ::: "memory");
        __builtin_amdgcn_sched_barrier(0);
        bad = 0u;
        #pragma unroll
        for (int j = 0; j < 16; ++j) {
          bad |= (g[j][0] >> 16) ^ texp;
          bad |= (g[j][1] >> 16) ^ texp;
          bad |= (g[j][2] >> 16) ^ texp;
          bad |= (g[j][3] >> 16) ^ texp;
        }
        if (!__any(bad != 0u)) break;
        #pragma unroll
        for (int j = 0; j < 16; ++j) GLOAD(j);
      }
    }
    __builtin_amdgcn_sched_barrier(0);

    // ---- 4: pack pairs -> f16 and stage into hsh (same layout as r9) ----
    #pragma unroll
    for (int j = 0; j < 8; ++j) {
      u32x4 pk;
      pk[0] = (g[2 * j][0] & 0xffffu)     | (g[2 * j][1] << 16);
      pk[1] = (g[2 * j][2] & 0xffffu)     | (g[2 * j][3] << 16);
      pk[2] = (g[2 * j + 1][0] & 0xffffu) | (g[2 * j + 1][1] << 16);
      pk[3] = (g[2 * j + 1][2] & 0xffffu) | (g[2 * j + 1][3] << 16);
      *(u32x4*)(hsh + (grow << 11) + ((gcb + j * 16) ^ gsw)) = pk;
    }

    // ---- 5: issue x(t+1) HBM prefetch (hides under hproj+gates) ----
    if (t + 1 < T_SZ) x_issue(x, b0, tid, t + 1, xst);

    // ---- 6: barrier: hsh fully staged ----
    asm volatile("s_waitcnt lgkmcnt(0)" ::: "memory");
    __builtin_amdgcn_s_barrier();
    __builtin_amdgcn_sched_barrier(0);

    // ---- 7: h projection (no mid barriers) ----
    #pragma unroll
    for (int ks = 0; ks < 32; ++ks) HPROJ(ks);

    // ---- 8: gates ----
    float hnf[4];
    #pragma unroll
    for (int r = 0; r < 4; ++r) {
      const float v  = acc[0][r] + acc[1][r] + acc[2][r] + acc[3][r];
      const float sc = (q == 2) ? 2.f : 1.f;
      const float s  = 1.f / (1.f + __expf(-sc * v));
      const float av = (q == 2) ? (2.f * s - 1.f) : s;   // tanh via 2*sigm(2x)-1
      const float x1 = __shfl_xor(av, 1);
      const float x2 = __shfl_xor(av, 2);
      const float x3 = __shfl_xor(av, 3);
      const float gi = (q == 0) ? av : (q == 1) ? x1 : (q == 2) ? x2 : x3;
      const int m1 = q ^ 1;
      const float gf = (m1 == 0) ? av : (m1 == 1) ? x1 : (m1 == 2) ? x2 : x3;
      const int m2 = q ^ 2;
      const float gg = (m2 == 0) ? av : (m2 == 1) ? x1 : (m2 == 2) ? x2 : x3;
      const int m3 = q ^ 3;
      const float go = (m3 == 0) ? av : (m3 == 1) ? x1 : (m3 == 2) ? x2 : x3;
      const float cn = gf * cst[r] + gi * gg;
      const float s2 = 1.f / (1.f + __expf(-2.f * cn));
      hnf[r] = go * (2.f * s2 - 1.f);
      cst[r] = cn;
    }

    // ---- 9: publish tagged h(t+1) — no drain, no flag, no barrier ----
    if (t < T_SZ - 1 && q == 0) {
      unsigned* hp = hpair + (size_t)((t + 1) & 1) * HB;
      #pragma unroll
      for (int r = 0; r < 4; ++r) {
        const unsigned val = ((unsigned)(t + 1) << 16) | (unsigned)f2h(hnf[r]);
        const unsigned* dp = hp + (size_t)(b0 + lk * 4 + r) * H_SZ + n_glob;
        asm volatile("global_store_dword %0, %1, off sc0 sc1" :: "v"(dp), "v"(val) : "memory");
      }
    }

    // ---- 10: off-path: 4x4 shuffle transpose + packed hidden_seq store ----
    const unsigned c01 = (unsigned)f2h(hnf[0]) | ((unsigned)f2h(hnf[1]) << 16);
    const unsigned c23 = (unsigned)f2h(hnf[2]) | ((unsigned)f2h(hnf[3]) << 16);
    const unsigned t01 = __shfl_xor(c01, 4);
    const unsigned t23 = __shfl_xor(c23, 4);
    unsigned r01, r23;
    if (p & 1) { r01 = (t01 >> 16) | (c01 & 0xffff0000u); r23 = (t23 >> 16) | (c23 & 0xffff0000u); }
    else       { r01 = (c01 & 0xffffu) | (t01 << 16);     r23 = (c23 & 0xffffu) | (t23 << 16); }
    const unsigned x01 = __shfl_xor(r01, 8);
    const unsigned x23 = __shfl_xor(r23, 8);
    u32x2 hw;
    if (p < 2) { hw.x = r01; hw.y = x01; }
    else       { hw.x = x23; hw.y = r23; }

    if (q == 0) {
      const int row = b0 + lk * 4 + p;
      f32x4 of = { h2f((unsigned short)(hw.x & 0xffffu)), h2f((unsigned short)(hw.x >> 16)),
                   h2f((unsigned short)(hw.y & 0xffffu)), h2f((unsigned short)(hw.y >> 16)) };
      *(f32x4*)(out + (size_t)row * (T_SZ * H_SZ) + (size_t)t * H_SZ + cb) = of;
      if (t == T_SZ - 1) {
        #pragma unroll
        for (int r = 0; r < 4; ++r) {
          const int b = b0 + lk * 4 + r;
          out[HO + (size_t)b * H_SZ + n_glob] = hnf[r];
          out[CO + (size_t)b * H_SZ + n_glob] = cst[r];
        }
      }
    }

    // ---- 11: retire x loads (oldest 8; pub+out stay in flight), stage x ----
    if (t + 1 < T_SZ) {
      asm volatile("s_waitcnt vmcnt(5)" ::: "memory");
      __builtin_amdgcn_sched_barrier(0);
      x_write(xl_nxt, tid, xst);
    }
    // ---- 12: end barrier (hsh reads done before next step's staging) ----
    asm volatile("s_waitcnt lgkmcnt(0)" ::: "memory");
    __builtin_amdgcn_s_barrier();
    __builtin_amdgcn_sched_barrier(0);
  }
#undef XPROJ
#undef HPROJ
#undef GLOAD
}

extern "C" void kernel_launch(void* const* d_in, const int* in_sizes, int n_in,
                              void* d_out, int out_size, void* d_ws, size_t ws_size,
                              hipStream_t stream) {
  const float* x = (const float*)d_in[0];
  const float* U[4]  = {(const float*)d_in[1], (const float*)d_in[4],
                        (const float*)d_in[7], (const float*)d_in[10]};
  const float* V[4]  = {(const float*)d_in[2], (const float*)d_in[5],
                        (const float*)d_in[8], (const float*)d_in[11]};
  const float* bb[4] = {(const float*)d_in[3], (const float*)d_in[6],
                        (const float*)d_in[9], (const float*)d_in[12]};
  float* out = (float*)d_out;

  char* p = (char*)d_ws;
  _Float16* Ubt = (_Float16*)p; p += (size_t)G4 * I_SZ * 2;          // 4 MB
  _Float16* Vt  = (_Float16*)p; p += (size_t)G4 * H_SZ * 2;          // 8 MB
  float*    biasw = (float*)p;  p += (size_t)G4 * 4;                 // 16 KB
  unsigned* hpair = (unsigned*)p;                                    // 512 KB

  for (int qq = 0; qq < 4; ++qq)
    hipLaunchKernelGGL(trans_kernel, dim3(16, 8), dim3(256), 0, stream, U[qq], Ubt, I_SZ, qq);
  for (int qq = 0; qq < 4; ++qq)
    hipLaunchKernelGGL(trans_kernel, dim3(16, 16), dim3(256), 0, stream, V[qq], Vt, H_SZ, qq);
  hipLaunchKernelGGL(bias_kernel, dim3(16), dim3(256), 0, stream, bb[0], bb[1], bb[2], bb[3], biasw);

  // both ring slots zeroed each call: slot0 = (tag0 | h0=0) satisfies t=0
  // immediately; slot1's zeros never match any expected tag (graph-replay safe)
  hipMemsetAsync(hpair, 0, (size_t)2 * HB * 4, stream);

  hipLaunchKernelGGL(lstm_recur, dim3(NBLK), dim3(256), 0, stream,
                     x, Ubt, Vt, biasw, out, hpair);
}

// Round 14
// 4284.066 us; speedup vs baseline: 1.4779x; 1.4779x over previous
//
#include <hip/hip_runtime.h>

typedef __attribute__((ext_vector_type(8))) _Float16 f16x8;
typedef __attribute__((ext_vector_type(4))) _Float16 f16x4;
typedef __attribute__((ext_vector_type(4))) float f32x4;
typedef __attribute__((ext_vector_type(2))) unsigned int u32x2;

#define B_SZ 64
#define T_SZ 512
#define I_SZ 512
#define H_SZ 1024
#define G4   4096
#define NBLK 128

// ---------- prep: transpose + gate-interleave weights ----------
// src: [R][1024] fp32 (gate q's U or V). dst: [4096][R] f16, dst[4*n+q][r] = src[r][n]
__global__ void trans_kernel(const float* __restrict__ src, _Float16* __restrict__ dst,
                             int R, int q) {
  __shared__ float tile[64][65];
  const int n0 = blockIdx.x * 64;
  const int r0 = blockIdx.y * 64;
  const int x = threadIdx.x & 63, y = threadIdx.x >> 6;
  #pragma unroll
  for (int it = 0; it < 16; ++it) {
    int r = y * 16 + it;
    tile[r][x] = src[(size_t)(r0 + r) * H_SZ + n0 + x];
  }
  __syncthreads();
  #pragma unroll
  for (int it = 0; it < 16; ++it) {
    int rn = y * 16 + it;
    dst[(size_t)(4 * (n0 + rn) + q) * R + r0 + x] = (_Float16)tile[x][rn];
  }
}

// ---------- prep: interleave bias ----------
__global__ void bias_kernel(const float* __restrict__ b0, const float* __restrict__ b1,
                            const float* __restrict__ b2, const float* __restrict__ b3,
                            float* __restrict__ dst) {
  int g = blockIdx.x * blockDim.x + threadIdx.x;
  if (g >= G4) return;
  int q = g & 3, n = g >> 2;
  const float* s = (q == 0) ? b0 : (q == 1) ? b1 : (q == 2) ? b2 : b3;
  dst[g] = s[n];
}

__device__ __forceinline__ float h2f(unsigned short u) {
  union { unsigned short s; _Float16 h; } c; c.s = u; return (float)c.h;
}
__device__ __forceinline__ unsigned short f2h(float f) {
  union { unsigned short s; _Float16 h; } c; c.h = (_Float16)f; return c.s;
}

// x prefetch: all 256 threads, 8x16B f32 chunks, linear source (coalesced)
__device__ __forceinline__ void x_issue(const float* x, int b0, int tid, int t, f32x4* xst) {
  #pragma unroll
  for (int j = 0; j < 8; ++j) {
    const int byteoff = j * 4096 + tid * 16;   // f32-slice byte offset
    const int row  = byteoff >> 11;            // 2048 B per f32 row
    const int colb = byteoff & 2047;
    const char* sp = (const char*)x + (((size_t)(b0 + row) * T_SZ + t) * I_SZ) * 4 + colb;
    asm volatile("global_load_dwordx4 %0, %1, off" : "=v"(xst[j]) : "v"(sp) : "memory");
  }
}
// cvt f32->f16 once at stage time; write 8B chunks, XOR-swizzled (16B granules)
__device__ __forceinline__ void x_write(char* xl, int tid, const f32x4* xst) {
  #pragma unroll
  for (int j = 0; j < 8; ++j) {
    const int byteoff = j * 4096 + tid * 16;
    const int row  = byteoff >> 11;
    const int colb = (byteoff & 2047) >> 1;    // f16 byte offset, 8B-aligned
    f16x4 v = { (_Float16)xst[j].x, (_Float16)xst[j].y,
                (_Float16)xst[j].z, (_Float16)xst[j].w };
    *(f16x4*)(xl + (row << 10) + (colb ^ ((row & 7) << 4))) = v;
  }
}

// ---------- persistent recurrence: two interleaved chains per block ----------
// 128 blocks x 256 thr. blk = hgrp*2 + pr; block runs chains 2pr and 2pr+1
// phase-by-phase, sharing its weight registers. While chain A's h propagates
// through the LLC, the block computes chain B's phase (and vice versa) —
// the cross-XCD sync latency is hidden under the other chain's compute.
// Each phase body is the verified round-9 step body. x: per-chain single
// LDS slot, in-place swap; poller has zero outstanding VMEM.
__global__ __launch_bounds__(256, 1) void lstm_recur(
    const float* __restrict__ x,        // [B][T][I] fp32
    const _Float16* __restrict__ Ubt,   // [4096][512]  row 4n+q = U_q[:,n]
    const _Float16* __restrict__ Vt,    // [4096][1024] row 4n+q = V_q[:,n]
    const float* __restrict__ biasw,    // [4096] interleaved
    float* __restrict__ out,            // hidden_seq | h_T | c_T
    _Float16* __restrict__ hbuf,        // [4 chains][2 slots][16][1024] f16
    unsigned* __restrict__ bar)         // flags: chain c at bar + c*256
{
  __shared__ __align__(16) char hsh[32768];    // h slice [16][1024] f16, swizzled
  __shared__ __align__(16) char xlds[32768];   // x [2 chains][16][512] f16, in-place

  const int tid  = threadIdx.x;
  const int wv   = tid >> 6;
  const int lane = tid & 63;
  const int lc   = lane & 15;     // col-in-wave / A-row sel
  const int lk   = lane >> 4;     // k-group
  const int q    = lc & 3;        // gate id (0=i,1=f,2=g,3=o)
  const int p    = lc >> 2;       // quad id
  const int blk  = blockIdx.x;
  const int pr   = blk & 1;       // chain pair (chains 2pr, 2pr+1)
  const int hgrp = blk >> 1;      // 0..63
  const int col0 = hgrp * 64 + wv * 16;
  const int sw   = (lc & 7) << 4; // read-side swizzle

  // ---- stationary weights: load once, pin via opaque asm (shared by both chains) ----
  f16x8 bU[16];
  f16x8 bV[32];
  {
    const _Float16* up = Ubt + (size_t)(col0 + lc) * I_SZ + lk * 8;
    #pragma unroll
    for (int ks = 0; ks < 16; ++ks) bU[ks] = *(const f16x8*)(up + ks * 32);
    const _Float16* vp = Vt + (size_t)(col0 + lc) * H_SZ + lk * 8;
    #pragma unroll
    for (int ks = 0; ks < 32; ++ks) bV[ks] = *(const f16x8*)(vp + ks * 32);
  }
  #pragma unroll
  for (int ks = 0; ks < 16; ++ks) asm volatile("" : "+v"(bU[ks]));
  #pragma unroll
  for (int ks = 0; ks < 32; ++ks) asm volatile("" : "+v"(bV[ks]));

  const float bias_v = biasw[col0 + lc];
  const int n_glob = hgrp * 16 + wv * 4 + p;
  const int cb     = hgrp * 16 + wv * 4;
  const size_t HO = (size_t)B_SZ * T_SZ * H_SZ;
  const size_t CO = HO + (size_t)B_SZ * H_SZ;

  float cst2[2][4] = {{0.f, 0.f, 0.f, 0.f}, {0.f, 0.f, 0.f, 0.f}};

  // gather geometry (each thread owns one local h-row's 2 KB in 8 chunks)
  const int grow = tid >> 4;            // 0..15 (local batch row)
  const int gkb  = (tid & 15) * 16;     // k-byte base
  const int gsw  = (grow & 7) << 4;

  // ---- prime: x(0) for both chains, then chain0's x(1) pending ----
  f32x4 xst[8];
  x_issue(x, pr * 32, tid, 0, xst);
  asm volatile("s_waitcnt vmcnt(0)" ::: "memory");
  __builtin_amdgcn_sched_barrier(0);
  x_write(xlds, tid, xst);
  x_issue(x, pr * 32 + 16, tid, 0, xst);
  asm volatile("s_waitcnt vmcnt(0)" ::: "memory");
  __builtin_amdgcn_sched_barrier(0);
  x_write(xlds + 16384, tid, xst);
  x_issue(x, pr * 32, tid, 1, xst);   // pending x0(1)
  asm volatile("s_waitcnt lgkmcnt(0)" ::: "memory");
  __builtin_amdgcn_s_barrier();
  __builtin_amdgcn_sched_barrier(0);

#define XPROJ(ks) { \
    const f16x8 a_ = *(const f16x8*)(xsl + (lc << 10) + ((((ks) * 64) + lk * 16) ^ sw)); \
    acc[(ks) & 3] = __builtin_amdgcn_mfma_f32_16x16x32_f16(a_, bU[(ks)], acc[(ks) & 3], 0, 0, 0); }
#define HPROJ(ks) { \
    const f16x8 hv = *(const f16x8*)(hsh + (lc << 11) + (((lk * 16) + (ks) * 64) ^ sw)); \
    acc[(ks) & 3] = __builtin_amdgcn_mfma_f32_16x16x32_f16(hv, bV[(ks)], acc[(ks) & 3], 0, 0, 0); }

  for (int t = 0; t < T_SZ; ++t) {
    #pragma unroll
    for (int ph = 0; ph < 2; ++ph) {
      const int c  = pr * 2 + ph;
      const int b0 = c * 16;
      _Float16* hb = hbuf + (size_t)c * 32768;
      const _Float16* hcur  = hb + (size_t)(t & 1) * 16384;
      _Float16*       hnext = hb + (size_t)((t + 1) & 1) * 16384;
      unsigned* flags = bar + c * 256;
      char* xsl = xlds + ph * 16384;
      const bool xiss = (ph == 0) ? (t + 1 < T_SZ) : (t + 2 < T_SZ);

      f32x4 acc[4];
      acc[0] = f32x4{bias_v, bias_v, bias_v, bias_v};
      acc[1] = f32x4{0.f, 0.f, 0.f, 0.f};
      acc[2] = f32x4{0.f, 0.f, 0.f, 0.f};
      acc[3] = f32x4{0.f, 0.f, 0.f, 0.f};

      // ---- a: x projection from this chain's LDS slot ----
      #pragma unroll
      for (int ks = 0; ks < 16; ++ks) XPROJ(ks);

      // ---- b: retire pending x-batch + old out-store (both old -> cheap) ----
      asm volatile("s_waitcnt vmcnt(0)" ::: "memory");
      __builtin_amdgcn_sched_barrier(0);
      // ---- c: all waves done reading xsl ----
      __builtin_amdgcn_s_barrier();
      __builtin_amdgcn_sched_barrier(0);
      // ---- d: in-place swap: write this chain's x(t+1) ----
      if (t + 1 < T_SZ) x_write(xsl, tid, xst);

      // ---- f: poll (wave0 has ZERO outstanding VMEM -> pure LLC RT) ----
      if (t) {
        if (wv == 0) {
          const unsigned* fp = flags + lane;
          unsigned v;
          do {
            asm volatile("global_load_dword %0, %1, off sc0 sc1\n\ts_waitcnt vmcnt(0)"
                         : "=&v"(v) : "v"(fp) : "memory");
          } while (__any(v < (unsigned)t));
        }
        __builtin_amdgcn_s_barrier();
        __builtin_amdgcn_sched_barrier(0);
      }

      // ---- h: issue h_c(t) gather from LLC ----
      f16x8 st0, st1, st2, st3, st4, st5, st6, st7;
      {
        const char* src = (const char*)hcur + grow * 2048 + gkb;
        asm volatile("global_load_dwordx4 %0, %1, off sc0 sc1" : "=v"(st0) : "v"(src)          : "memory");
        asm volatile("global_load_dwordx4 %0, %1, off sc0 sc1" : "=v"(st1) : "v"(src + 256)    : "memory");
        asm volatile("global_load_dwordx4 %0, %1, off sc0 sc1" : "=v"(st2) : "v"(src + 512)    : "memory");
        asm volatile("global_load_dwordx4 %0, %1, off sc0 sc1" : "=v"(st3) : "v"(src + 768)    : "memory");
        asm volatile("global_load_dwordx4 %0, %1, off sc0 sc1" : "=v"(st4) : "v"(src + 1024)   : "memory");
        asm volatile("global_load_dwordx4 %0, %1, off sc0 sc1" : "=v"(st5) : "v"(src + 1280)   : "memory");
        asm volatile("global_load_dwordx4 %0, %1, off sc0 sc1" : "=v"(st6) : "v"(src + 1536)   : "memory");
        asm volatile("global_load_dwordx4 %0, %1, off sc0 sc1" : "=v"(st7) : "v"(src + 1792)   : "memory");
      }
      // ---- e: issue next x-batch AFTER gather (retired by counted vmcnt) ----
      if (ph == 0) { if (t + 1 < T_SZ) x_issue(x, b0 + 16, tid, t + 1, xst); }
      else         { if (t + 2 < T_SZ) x_issue(x, b0 - 16, tid, t + 2, xst); }

      // ---- i: first k-half ready (in-order retire: st0-3 oldest) ----
      if (xiss) asm volatile("s_waitcnt vmcnt(12)" ::: "memory");
      else      asm volatile("s_waitcnt vmcnt(4)"  ::: "memory");
      __builtin_amdgcn_sched_barrier(0);
      *(f16x8*)(hsh + (grow << 11) + ((gkb +   0) ^ gsw)) = st0;
      *(f16x8*)(hsh + (grow << 11) + ((gkb + 256) ^ gsw)) = st1;
      *(f16x8*)(hsh + (grow << 11) + ((gkb + 512) ^ gsw)) = st2;
      *(f16x8*)(hsh + (grow << 11) + ((gkb + 768) ^ gsw)) = st3;
      asm volatile("s_waitcnt lgkmcnt(0)" ::: "memory");
      __builtin_amdgcn_s_barrier();
      __builtin_amdgcn_sched_barrier(0);

      // ---- k: h-proj first half (second k-half still in flight) ----
      #pragma unroll
      for (int ks = 0; ks < 16; ++ks) HPROJ(ks);

      // ---- l: second k-half ----
      if (xiss) asm volatile("s_waitcnt vmcnt(8)" ::: "memory");
      else      asm volatile("s_waitcnt vmcnt(0)" ::: "memory");
      __builtin_amdgcn_sched_barrier(0);
      *(f16x8*)(hsh + (grow << 11) + ((gkb + 1024) ^ gsw)) = st4;
      *(f16x8*)(hsh + (grow << 11) + ((gkb + 1280) ^ gsw)) = st5;
      *(f16x8*)(hsh + (grow << 11) + ((gkb + 1536) ^ gsw)) = st6;
      *(f16x8*)(hsh + (grow << 11) + ((gkb + 1792) ^ gsw)) = st7;
      asm volatile("s_waitcnt lgkmcnt(0)" ::: "memory");
      __builtin_amdgcn_s_barrier();
      __builtin_amdgcn_sched_barrier(0);

      // ---- m: h-proj second half ----
      #pragma unroll
      for (int ks = 16; ks < 32; ++ks) HPROJ(ks);

      // ---- n: gates ----
      float hnf[4];
      #pragma unroll
      for (int r = 0; r < 4; ++r) {
        const float v  = acc[0][r] + acc[1][r] + acc[2][r] + acc[3][r];
        const float sc = (q == 2) ? 2.f : 1.f;
        const float s  = 1.f / (1.f + __expf(-sc * v));
        const float av = (q == 2) ? (2.f * s - 1.f) : s;   // tanh via 2*sigm(2x)-1
        const float x1 = __shfl_xor(av, 1);
        const float x2 = __shfl_xor(av, 2);
        const float x3 = __shfl_xor(av, 3);
        const float gi = (q == 0) ? av : (q == 1) ? x1 : (q == 2) ? x2 : x3;
        const int m1 = q ^ 1;
        const float gf = (m1 == 0) ? av : (m1 == 1) ? x1 : (m1 == 2) ? x2 : x3;
        const int m2 = q ^ 2;
        const float gg = (m2 == 0) ? av : (m2 == 1) ? x1 : (m2 == 2) ? x2 : x3;
        const int m3 = q ^ 3;
        const float go = (m3 == 0) ? av : (m3 == 1) ? x1 : (m3 == 2) ? x2 : x3;
        const float cn = gf * cst2[ph][r] + gi * gg;
        const float s2 = 1.f / (1.f + __expf(-2.f * cn));
        hnf[r] = go * (2.f * s2 - 1.f);
        cst2[ph][r] = cn;
      }

      // ---- o: 4x4 shuffle transpose: lane p -> local row lk*4+p, cols cb.. ----
      const unsigned c01 = (unsigned)f2h(hnf[0]) | ((unsigned)f2h(hnf[1]) << 16);
      const unsigned c23 = (unsigned)f2h(hnf[2]) | ((unsigned)f2h(hnf[3]) << 16);
      const unsigned t01 = __shfl_xor(c01, 4);
      const unsigned t23 = __shfl_xor(c23, 4);
      unsigned r01, r23;
      if (p & 1) { r01 = (t01 >> 16) | (c01 & 0xffff0000u); r23 = (t23 >> 16) | (c23 & 0xffff0000u); }
      else       { r01 = (c01 & 0xffffu) | (t01 << 16);     r23 = (c23 & 0xffffu) | (t23 << 16); }
      const unsigned x01 = __shfl_xor(r01, 8);
      const unsigned x23 = __shfl_xor(r23, 8);
      u32x2 hw;
      if (p < 2) { hw.x = r01; hw.y = x01; }
      else       { hw.x = x23; hw.y = r23; }

      const int rloc = lk * 4 + p;

      // ---- p: publish h (LLC), drain, barrier, flag ----
      if (t < T_SZ - 1) {
        if (q == 0) {
          _Float16* hp2 = hnext + (size_t)rloc * H_SZ + cb;
          asm volatile("global_store_dwordx2 %0, %1, off sc0 sc1" :: "v"(hp2), "v"(hw) : "memory");
        }
        asm volatile("s_waitcnt vmcnt(0)" ::: "memory");
        __builtin_amdgcn_s_barrier();
        if (tid == 64) {
          const unsigned* fp = flags + hgrp;
          unsigned tv = (unsigned)(t + 1);
          asm volatile("global_store_dword %0, %1, off sc0 sc1" :: "v"(fp), "v"(tv) : "memory");
        }
      }

      // ---- q: hidden_seq store (off the critical path) ----
      if (q == 0) {
        const int row = b0 + rloc;
        f32x4 of = { h2f((unsigned short)(hw.x & 0xffffu)), h2f((unsigned short)(hw.x >> 16)),
                     h2f((unsigned short)(hw.y & 0xffffu)), h2f((unsigned short)(hw.y >> 16)) };
        *(f32x4*)(out + (size_t)row * (T_SZ * H_SZ) + (size_t)t * H_SZ + cb) = of;
        if (t == T_SZ - 1) {
          #pragma unroll
          for (int r = 0; r < 4; ++r) {
            const int b = b0 + lk * 4 + r;
            out[HO + (size_t)b * H_SZ + n_glob] = hnf[r];
            out[CO + (size_t)b * H_SZ + n_glob] = cst2[ph][r];
          }
        }
      }
    }
  }
#undef XPROJ
#undef HPROJ
}

extern "C" void kernel_launch(void* const* d_in, const int* in_sizes, int n_in,
                              void* d_out, int out_size, void* d_ws, size_t ws_size,
                              hipStream_t stream) {
  const float* x = (const float*)d_in[0];
  const float* U[4]  = {(const float*)d_in[1], (const float*)d_in[4],
                        (const float*)d_in[7], (const float*)d_in[10]};
  const float* V[4]  = {(const float*)d_in[2], (const float*)d_in[5],
                        (const float*)d_in[8], (const float*)d_in[11]};
  const float* bb[4] = {(const float*)d_in[3], (const float*)d_in[6],
                        (const float*)d_in[9], (const float*)d_in[12]};
  float* out = (float*)d_out;

  char* p = (char*)d_ws;
  _Float16* Ubt = (_Float16*)p; p += (size_t)G4 * I_SZ * 2;          // 4 MB
  _Float16* Vt  = (_Float16*)p; p += (size_t)G4 * H_SZ * 2;          // 8 MB
  float*    biasw = (float*)p;  p += (size_t)G4 * 4;                 // 16 KB
  _Float16* hbuf  = (_Float16*)p; p += (size_t)4 * 2 * 16 * H_SZ * 2; // 256 KB
  unsigned* bar   = (unsigned*)p;                                    // 4 KB

  for (int qq = 0; qq < 4; ++qq)
    hipLaunchKernelGGL(trans_kernel, dim3(16, 8), dim3(256), 0, stream, U[qq], Ubt, I_SZ, qq);
  for (int qq = 0; qq < 4; ++qq)
    hipLaunchKernelGGL(trans_kernel, dim3(16, 16), dim3(256), 0, stream, V[qq], Vt, H_SZ, qq);
  hipLaunchKernelGGL(bias_kernel, dim3(16), dim3(256), 0, stream, bb[0], bb[1], bb[2], bb[3], biasw);

  // h(0)=0 for all chains (both slots); flags = 0 (graph-replay safe)
  hipMemsetAsync(hbuf, 0, (size_t)4 * 2 * 16 * H_SZ * 2, stream);
  hipMemsetAsync(bar, 0, 4096, stream);

  hipLaunchKernelGGL(lstm_recur, dim3(NBLK), dim3(256), 0, stream,
                     x, Ubt, Vt, biasw, out, hbuf, bar);
}

// Round 15
// 1867.171 us; speedup vs baseline: 3.3910x; 2.2944x over previous
//
#include <hip/hip_runtime.h>

typedef __attribute__((ext_vector_type(8))) _Float16 f16x8;
typedef __attribute__((ext_vector_type(4))) _Float16 f16x4;
typedef __attribute__((ext_vector_type(4))) float f32x4;

#define B_SZ 64
#define T_SZ 512
#define I_SZ 512
#define H_SZ 1024
#define G4   4096
#define NBLK 256

// ---------- prep: transpose + gate-interleave weights ----------
// src: [R][1024] fp32 (gate q's U or V). dst: [4096][R] f16, dst[4*n+q][r] = src[r][n]
__global__ void trans_kernel(const float* __restrict__ src, _Float16* __restrict__ dst,
                             int R, int q) {
  __shared__ float tile[64][65];
  const int n0 = blockIdx.x * 64;
  const int r0 = blockIdx.y * 64;
  const int x = threadIdx.x & 63, y = threadIdx.x >> 6;
  #pragma unroll
  for (int it = 0; it < 16; ++it) {
    int r = y * 16 + it;
    tile[r][x] = src[(size_t)(r0 + r) * H_SZ + n0 + x];
  }
  __syncthreads();
  #pragma unroll
  for (int it = 0; it < 16; ++it) {
    int rn = y * 16 + it;
    dst[(size_t)(4 * (n0 + rn) + q) * R + r0 + x] = (_Float16)tile[x][rn];
  }
}

// ---------- prep: interleave bias ----------
__global__ void bias_kernel(const float* __restrict__ b0, const float* __restrict__ b1,
                            const float* __restrict__ b2, const float* __restrict__ b3,
                            float* __restrict__ dst) {
  int g = blockIdx.x * blockDim.x + threadIdx.x;
  if (g >= G4) return;
  int q = g & 3, n = g >> 2;
  const float* s = (q == 0) ? b0 : (q == 1) ? b1 : (q == 2) ? b2 : b3;
  dst[g] = s[n];
}

__device__ __forceinline__ unsigned short f2h(float f) {
  union { unsigned short s; _Float16 h; } c; c.h = (_Float16)f; return c.s;
}

// x prefetch: all 256 threads, 8x16B f32 chunks, linear source (coalesced)
__device__ __forceinline__ void x_issue(const float* x, int b0, int tid, int t, f32x4* xst) {
  #pragma unroll
  for (int j = 0; j < 8; ++j) {
    const int byteoff = j * 4096 + tid * 16;   // f32-slice byte offset
    const int row  = byteoff >> 11;            // 2048 B per f32 row
    const int colb = byteoff & 2047;
    const char* sp = (const char*)x + (((size_t)(b0 + row) * T_SZ + t) * I_SZ) * 4 + colb;
    asm volatile("global_load_dwordx4 %0, %1, off" : "=v"(xst[j]) : "v"(sp) : "memory");
  }
}
// cvt f32->f16 once at stage time; write 8B chunks, XOR-swizzled (16B granules)
__device__ __forceinline__ void x_write(char* xl, int tid, const f32x4* xst) {
  #pragma unroll
  for (int j = 0; j < 8; ++j) {
    const int byteoff = j * 4096 + tid * 16;
    const int row  = byteoff >> 11;
    const int colb = (byteoff & 2047) >> 1;    // f16 byte offset, 8B-aligned
    f16x4 v = { (_Float16)xst[j].x, (_Float16)xst[j].y,
                (_Float16)xst[j].z, (_Float16)xst[j].w };
    *(f16x4*)(xl + (row << 10) + (colb ^ ((row & 7) << 4))) = v;
  }
}

// ---------- persistent recurrence ----------
// r9 skeleton (verified PASS @2266us). Single delta: MFMA operands swapped —
// A = weight fragments (U^T/V^T rows = gate cols), B = x/h fragments. The
// A/B fragment register addressing is identical (both read [row|col=lane&15]
// [k=(lane>>4)*8+j] from transposed storage), so register contents and all
// LDS reads are unchanged; only the intrinsic arg order differs. Output
// becomes D[gate][batch]: each lane holds i,f,g,o of ONE (batch,hidden) pair
// -> zero-shuffle gates, 5 exps (was 8), scalar c-state, no 4x4 transpose.
__global__ __launch_bounds__(256, 1) void lstm_recur(
    const float* __restrict__ x,        // [B][T][I] fp32
    const _Float16* __restrict__ Ubt,   // [4096][512]  row 4n+q = U_q[:,n]
    const _Float16* __restrict__ Vt,    // [4096][1024] row 4n+q = V_q[:,n]
    const float* __restrict__ biasw,    // [4096] interleaved
    float* __restrict__ out,            // hidden_seq | h_T | c_T
    _Float16* __restrict__ hbuf,        // [2][64][1024] f16 double buffer
    unsigned* __restrict__ bar)         // flags: chain bgrp at bar + bgrp*256
{
  __shared__ __align__(16) char hsh[32768];    // h slice [16][1024] f16, swizzled
  __shared__ __align__(16) char xlds[32768];   // x dbuf [2][16][512] f16, swizzled

  const int tid  = threadIdx.x;
  const int wv   = tid >> 6;
  const int lane = tid & 63;
  const int lc   = lane & 15;     // fragment row/col selector = BATCH now
  const int lk   = lane >> 4;     // k-group; also hidden-unit selector in D
  const int blk  = blockIdx.x;
  const int bgrp = blk & 3;       // batch chain (XCD pair)
  const int hgrp = blk >> 2;      // 0..63
  const int col0 = hgrp * 64 + wv * 16;
  const int b0   = bgrp * 16;
  const int sw   = (lc & 7) << 4; // read-side swizzle

  unsigned* flags = bar + bgrp * 256;   // 64 dwords per chain

  // ---- stationary weights: load once, pin via opaque asm ----
  f16x8 bU[16];
  f16x8 bV[32];
  {
    const _Float16* up = Ubt + (size_t)(col0 + lc) * I_SZ + lk * 8;
    #pragma unroll
    for (int ks = 0; ks < 16; ++ks) bU[ks] = *(const f16x8*)(up + ks * 32);
    const _Float16* vp = Vt + (size_t)(col0 + lc) * H_SZ + lk * 8;
    #pragma unroll
    for (int ks = 0; ks < 32; ++ks) bV[ks] = *(const f16x8*)(vp + ks * 32);
  }
  #pragma unroll
  for (int ks = 0; ks < 16; ++ks) asm volatile("" : "+v"(bU[ks]));
  #pragma unroll
  for (int ks = 0; ks < 32; ++ks) asm volatile("" : "+v"(bV[ks]));

  // D[row=gate: col0+lk*4+r][col=batch: b0+lc]
  const f32x4 bias4 = *(const f32x4*)(biasw + col0 + lk * 4);
  const int n_gl = hgrp * 16 + wv * 4 + lk;   // hidden unit this lane owns
  const int brow = b0 + lc;                   // batch row this lane owns
  const size_t HO = (size_t)B_SZ * T_SZ * H_SZ;
  const size_t CO = HO + (size_t)B_SZ * H_SZ;

  float cst = 0.f;   // c-state: ONE (batch, hidden) pair per lane

  // gather geometry (each thread owns one h-row's 2 KB in 8 chunks)
  const int grow = tid >> 4;            // 0..15 (batch row)
  const int gkb  = (tid & 15) * 16;     // k-byte base
  const int gsw  = (grow & 7) << 4;

  // ---- prime x(0) into xlds[0] ----
  f32x4 xst[8];
  x_issue(x, b0, tid, 0, xst);
  asm volatile("s_waitcnt vmcnt(0)" ::: "memory");
  __builtin_amdgcn_sched_barrier(0);
  x_write(xlds, tid, xst);
  asm volatile("s_waitcnt lgkmcnt(0)" ::: "memory");
  __builtin_amdgcn_s_barrier();
  __builtin_amdgcn_sched_barrier(0);

#define XPROJ(ks) { \
    const f16x8 a_ = *(const f16x8*)(xl_cur + (lc << 10) + ((((ks) * 64) + lk * 16) ^ sw)); \
    acc[(ks) & 3] = __builtin_amdgcn_mfma_f32_16x16x32_f16(bU[(ks)], a_, acc[(ks) & 3], 0, 0, 0); }
#define HPROJ(ks) { \
    const f16x8 hv = *(const f16x8*)(hsh + (lc << 11) + (((lk * 16) + (ks) * 64) ^ sw)); \
    acc[(ks) & 3] = __builtin_amdgcn_mfma_f32_16x16x32_f16(bV[(ks)], hv, acc[(ks) & 3], 0, 0, 0); }

  for (int t = 0; t < T_SZ; ++t) {
    const _Float16* hcur  = hbuf + (size_t)(t & 1) * (B_SZ * H_SZ);
    _Float16*       hnext = hbuf + (size_t)((t + 1) & 1) * (B_SZ * H_SZ);
    char* xl_cur = xlds + (size_t)(t & 1) * 16384;
    char* xl_nxt = xlds + (size_t)((t + 1) & 1) * 16384;

    // ---- 1: issue x(t+1) prefetch (in flight across x-proj + poll) ----
    if (t + 1 < T_SZ) x_issue(x, b0, tid, t + 1, xst);

    f32x4 acc[4];
    acc[0] = bias4;
    acc[1] = f32x4{0.f, 0.f, 0.f, 0.f};
    acc[2] = f32x4{0.f, 0.f, 0.f, 0.f};
    acc[3] = f32x4{0.f, 0.f, 0.f, 0.f};

    // ---- 2: x projection (pre-poll: off the serial chain, absorbs skew) ----
    #pragma unroll
    for (int ks = 0; ks < 16; ++ks) XPROJ(ks);

    // ---- 3: wave0 polls all 64 producer flags ----
    if (t) {
      if (wv == 0) {
        const unsigned* fp = flags + lane;
        unsigned v;
        do {
          asm volatile("global_load_dword %0, %1, off sc0 sc1\n\ts_waitcnt vmcnt(0)"
                       : "=&v"(v) : "v"(fp) : "memory");
        } while (__any(v < (unsigned)t));
      }
      __builtin_amdgcn_s_barrier();
      __builtin_amdgcn_sched_barrier(0);
    }

    // ---- 4: issue h(t) gather from LLC, k-split halves ----
    f16x8 st0, st1, st2, st3, st4, st5, st6, st7;
    {
      const char* src = (const char*)(hcur + (size_t)b0 * H_SZ) + grow * 2048 + gkb;
      asm volatile("global_load_dwordx4 %0, %1, off sc0 sc1" : "=v"(st0) : "v"(src)          : "memory");
      asm volatile("global_load_dwordx4 %0, %1, off sc0 sc1" : "=v"(st1) : "v"(src + 256)    : "memory");
      asm volatile("global_load_dwordx4 %0, %1, off sc0 sc1" : "=v"(st2) : "v"(src + 512)    : "memory");
      asm volatile("global_load_dwordx4 %0, %1, off sc0 sc1" : "=v"(st3) : "v"(src + 768)    : "memory");
      asm volatile("global_load_dwordx4 %0, %1, off sc0 sc1" : "=v"(st4) : "v"(src + 1024)   : "memory");
      asm volatile("global_load_dwordx4 %0, %1, off sc0 sc1" : "=v"(st5) : "v"(src + 1280)   : "memory");
      asm volatile("global_load_dwordx4 %0, %1, off sc0 sc1" : "=v"(st6) : "v"(src + 1536)   : "memory");
      asm volatile("global_load_dwordx4 %0, %1, off sc0 sc1" : "=v"(st7) : "v"(src + 1792)   : "memory");
    }

    // ---- 5: first k-half ready (vmcnt(4): in-order retire -> st0-3 valid,
    //         and all older prefetch/out stores drained too) ----
    asm volatile("s_waitcnt vmcnt(4)" ::: "memory");
    __builtin_amdgcn_sched_barrier(0);
    *(f16x8*)(hsh + (grow << 11) + ((gkb +   0) ^ gsw)) = st0;
    *(f16x8*)(hsh + (grow << 11) + ((gkb + 256) ^ gsw)) = st1;
    *(f16x8*)(hsh + (grow << 11) + ((gkb + 512) ^ gsw)) = st2;
    *(f16x8*)(hsh + (grow << 11) + ((gkb + 768) ^ gsw)) = st3;
    asm volatile("s_waitcnt lgkmcnt(0)" ::: "memory");
    __builtin_amdgcn_s_barrier();
    __builtin_amdgcn_sched_barrier(0);

    // ---- 6: h-proj first half (overlaps second k-half still in flight) ----
    #pragma unroll
    for (int ks = 0; ks < 16; ++ks) HPROJ(ks);

    // ---- 7: second k-half + x(t+1) stage ----
    asm volatile("s_waitcnt vmcnt(0)" ::: "memory");
    __builtin_amdgcn_sched_barrier(0);
    *(f16x8*)(hsh + (grow << 11) + ((gkb + 1024) ^ gsw)) = st4;
    *(f16x8*)(hsh + (grow << 11) + ((gkb + 1280) ^ gsw)) = st5;
    *(f16x8*)(hsh + (grow << 11) + ((gkb + 1536) ^ gsw)) = st6;
    *(f16x8*)(hsh + (grow << 11) + ((gkb + 1792) ^ gsw)) = st7;
    if (t + 1 < T_SZ) x_write(xl_nxt, tid, xst);
    asm volatile("s_waitcnt lgkmcnt(0)" ::: "memory");
    __builtin_amdgcn_s_barrier();
    __builtin_amdgcn_sched_barrier(0);

    // ---- 8: h-proj second half ----
    #pragma unroll
    for (int ks = 16; ks < 32; ++ks) HPROJ(ks);

    // ---- 9: gates — all four in-lane (acc[·][r] row = gate q=r), no shuffles ----
    const float vi = acc[0][0] + acc[1][0] + acc[2][0] + acc[3][0];
    const float vf = acc[0][1] + acc[1][1] + acc[2][1] + acc[3][1];
    const float vg = acc[0][2] + acc[1][2] + acc[2][2] + acc[3][2];
    const float vo = acc[0][3] + acc[1][3] + acc[2][3] + acc[3][3];
    const float gi = 1.f / (1.f + __expf(-vi));
    const float gf = 1.f / (1.f + __expf(-vf));
    const float sg = 1.f / (1.f + __expf(-2.f * vg));
    const float gg = 2.f * sg - 1.f;                    // tanh
    const float go = 1.f / (1.f + __expf(-vo));
    const float cn = gf * cst + gi * gg;
    const float sc2 = 1.f / (1.f + __expf(-2.f * cn));
    const float hn = go * (2.f * sc2 - 1.f);
    cst = cn;

    // ---- 10: publish h (LLC, 2B/lane, all 64 lanes), drain, barrier, flag ----
    if (t < T_SZ - 1) {
      const unsigned short hv16 = f2h(hn);
      _Float16* hp2 = hnext + (size_t)brow * H_SZ + n_gl;
      asm volatile("global_store_short %0, %1, off sc0 sc1" :: "v"(hp2), "v"(hv16) : "memory");
    }
    asm volatile("s_waitcnt vmcnt(0)" ::: "memory");
    __builtin_amdgcn_s_barrier();
    if (t < T_SZ - 1 && tid == 64) {
      const unsigned* fp = flags + hgrp;
      unsigned tv = (unsigned)(t + 1);
      asm volatile("global_store_dword %0, %1, off sc0 sc1" :: "v"(fp), "v"(tv) : "memory");
    }

    // ---- 11: hidden_seq store (plain, off the critical path; lanes lk-adjacent
    //          in n coalesce to 16x16B per wave) ----
    out[(size_t)brow * (T_SZ * H_SZ) + (size_t)t * H_SZ + n_gl] = hn;
    if (t == T_SZ - 1) {
      out[HO + (size_t)brow * H_SZ + n_gl] = hn;
      out[CO + (size_t)brow * H_SZ + n_gl] = cn;
    }
  }
#undef XPROJ
#undef HPROJ
}

extern "C" void kernel_launch(void* const* d_in, const int* in_sizes, int n_in,
                              void* d_out, int out_size, void* d_ws, size_t ws_size,
                              hipStream_t stream) {
  const float* x = (const float*)d_in[0];
  const float* U[4]  = {(const float*)d_in[1], (const float*)d_in[4],
                        (const float*)d_in[7], (const float*)d_in[10]};
  const float* V[4]  = {(const float*)d_in[2], (const float*)d_in[5],
                        (const float*)d_in[8], (const float*)d_in[11]};
  const float* bb[4] = {(const float*)d_in[3], (const float*)d_in[6],
                        (const float*)d_in[9], (const float*)d_in[12]};
  float* out = (float*)d_out;

  char* p = (char*)d_ws;
  _Float16* Ubt = (_Float16*)p; p += (size_t)G4 * I_SZ * 2;          // 4 MB
  _Float16* Vt  = (_Float16*)p; p += (size_t)G4 * H_SZ * 2;          // 8 MB
  float*    biasw = (float*)p;  p += (size_t)G4 * 4;                 // 16 KB
  _Float16* hbuf  = (_Float16*)p; p += (size_t)2 * B_SZ * H_SZ * 2;  // 256 KB
  unsigned* bar   = (unsigned*)p;                                    // 16 KB

  for (int qq = 0; qq < 4; ++qq)
    hipLaunchKernelGGL(trans_kernel, dim3(16, 8), dim3(256), 0, stream, U[qq], Ubt, I_SZ, qq);
  for (int qq = 0; qq < 4; ++qq)
    hipLaunchKernelGGL(trans_kernel, dim3(16, 16), dim3(256), 0, stream, V[qq], Vt, H_SZ, qq);
  hipLaunchKernelGGL(bias_kernel, dim3(16), dim3(256), 0, stream, bb[0], bb[1], bb[2], bb[3], biasw);

  // h(0) = 0 (buffer 0 read at t=0); flags = 0 (graph-replay safe)
  hipMemsetAsync(hbuf, 0, (size_t)B_SZ * H_SZ * 2, stream);
  hipMemsetAsync(bar, 0, 16384, stream);

  hipLaunchKernelGGL(lstm_recur, dim3(NBLK), dim3(256), 0, stream,
                     x, Ubt, Vt, biasw, out, hbuf, bar);
}

// Round 16
// 1761.963 us; speedup vs baseline: 3.5935x; 1.0597x over previous
//
#include <hip/hip_runtime.h>

typedef __attribute__((ext_vector_type(8))) _Float16 f16x8;
typedef __attribute__((ext_vector_type(4))) _Float16 f16x4;
typedef __attribute__((ext_vector_type(4))) float f32x4;

#define B_SZ 64
#define T_SZ 512
#define I_SZ 512
#define H_SZ 1024
#define G4   4096
#define NBLK 256

// ---------- prep: transpose + gate-interleave weights ----------
// src: [R][1024] fp32 (gate q's U or V). dst: [4096][R] f16, dst[4*n+q][r] = src[r][n]
__global__ void trans_kernel(const float* __restrict__ src, _Float16* __restrict__ dst,
                             int R, int q) {
  __shared__ float tile[64][65];
  const int n0 = blockIdx.x * 64;
  const int r0 = blockIdx.y * 64;
  const int x = threadIdx.x & 63, y = threadIdx.x >> 6;
  #pragma unroll
  for (int it = 0; it < 16; ++it) {
    int r = y * 16 + it;
    tile[r][x] = src[(size_t)(r0 + r) * H_SZ + n0 + x];
  }
  __syncthreads();
  #pragma unroll
  for (int it = 0; it < 16; ++it) {
    int rn = y * 16 + it;
    dst[(size_t)(4 * (n0 + rn) + q) * R + r0 + x] = (_Float16)tile[x][rn];
  }
}

// ---------- prep: interleave bias ----------
__global__ void bias_kernel(const float* __restrict__ b0, const float* __restrict__ b1,
                            const float* __restrict__ b2, const float* __restrict__ b3,
                            float* __restrict__ dst) {
  int g = blockIdx.x * blockDim.x + threadIdx.x;
  if (g >= G4) return;
  int q = g & 3, n = g >> 2;
  const float* s = (q == 0) ? b0 : (q == 1) ? b1 : (q == 2) ? b2 : b3;
  dst[g] = s[n];
}

__device__ __forceinline__ unsigned short f2h(float f) {
  union { unsigned short s; _Float16 h; } c; c.h = (_Float16)f; return c.s;
}

// x prefetch: all 256 threads, 8x16B f32 chunks, linear source (coalesced)
__device__ __forceinline__ void x_issue(const float* x, int b0, int tid, int t, f32x4* xst) {
  #pragma unroll
  for (int j = 0; j < 8; ++j) {
    const int byteoff = j * 4096 + tid * 16;   // f32-slice byte offset
    const int row  = byteoff >> 11;            // 2048 B per f32 row
    const int colb = byteoff & 2047;
    const char* sp = (const char*)x + (((size_t)(b0 + row) * T_SZ + t) * I_SZ) * 4 + colb;
    asm volatile("global_load_dwordx4 %0, %1, off" : "=v"(xst[j]) : "v"(sp) : "memory");
  }
}
// cvt f32->f16 once at stage time; write 8B chunks, XOR-swizzled (16B granules)
__device__ __forceinline__ void x_write(char* xl, int tid, const f32x4* xst) {
  #pragma unroll
  for (int j = 0; j < 8; ++j) {
    const int byteoff = j * 4096 + tid * 16;
    const int row  = byteoff >> 11;
    const int colb = (byteoff & 2047) >> 1;    // f16 byte offset, 8B-aligned
    f16x4 v = { (_Float16)xst[j].x, (_Float16)xst[j].y,
                (_Float16)xst[j].z, (_Float16)xst[j].w };
    *(f16x4*)(xl + (row << 10) + (colb ^ ((row & 7) << 4))) = v;
  }
}

// ---------- persistent recurrence: K-partitioned waves ----------
// r15 sync machinery verbatim (flags, poll, publish, XCD map, x pipeline).
// Delta: wave wv owns ALL 64 gate-cols x K-quarter [wv*256, wv*256+256).
// h fragments load DIRECTLY from hbuf to VGPRs (address pattern mirrors the
// verified bV load: 8 contiguous k for fixed batch=lc) -> hsh LDS staging
// deleted; vmcnt staircase overlaps gather with MFMA. Per-wave partial sums
// (4 col-tiles x f32x4) reduce across waves via padded LDS pbuf; owner lane
// (batch=lc, hidden nl=wv*4+lk) adds bias and runs the zero-shuffle gates.
__global__ __launch_bounds__(256, 1) void lstm_recur(
    const float* __restrict__ x,        // [B][T][I] fp32
    const _Float16* __restrict__ Ubt,   // [4096][512]  row 4n+q = U_q[:,n]
    const _Float16* __restrict__ Vt,    // [4096][1024] row 4n+q = V_q[:,n]
    const float* __restrict__ biasw,    // [4096] interleaved
    float* __restrict__ out,            // hidden_seq | h_T | c_T
    _Float16* __restrict__ hbuf,        // [2][64][1024] f16 double buffer
    unsigned* __restrict__ bar)         // flags: chain bgrp at bar + bgrp*256
{
  __shared__ __align__(16) char xlds[32768];     // x dbuf [2][16][512] f16, swizzled
  __shared__ __align__(16) float pbuf[4][16][68]; // per-wave K-partials (+4 pad)

  const int tid  = threadIdx.x;
  const int wv   = tid >> 6;      // K-quarter this wave owns
  const int lane = tid & 63;
  const int lc   = lane & 15;     // batch selector (fragment col)
  const int lk   = lane >> 4;     // k-subgroup
  const int blk  = blockIdx.x;
  const int bgrp = blk & 3;       // batch chain (XCD pair)
  const int hgrp = blk >> 2;      // 0..63
  const int b0   = bgrp * 16;
  const int sw   = (lc & 7) << 4; // x read-side swizzle

  unsigned* flags = bar + bgrp * 256;   // 64 dwords per chain

  // ---- stationary weights: all 4 col-tiles x this wave's K-quarter ----
  f16x8 bU[16];   // [ct*4+ks], ks<4 : U^T[colg][wv*128 + ks*32 + lk*8]
  f16x8 bV[32];   // [ct*8+ks], ks<8 : V^T[colg][wv*256 + ks*32 + lk*8]
  #pragma unroll
  for (int ct = 0; ct < 4; ++ct) {
    const int colg = hgrp * 64 + ct * 16 + lc;
    const _Float16* up = Ubt + (size_t)colg * I_SZ + wv * 128 + lk * 8;
    #pragma unroll
    for (int ks = 0; ks < 4; ++ks) bU[ct * 4 + ks] = *(const f16x8*)(up + ks * 32);
    const _Float16* vp = Vt + (size_t)colg * H_SZ + wv * 256 + lk * 8;
    #pragma unroll
    for (int ks = 0; ks < 8; ++ks) bV[ct * 8 + ks] = *(const f16x8*)(vp + ks * 32);
  }
  #pragma unroll
  for (int ks = 0; ks < 16; ++ks) asm volatile("" : "+v"(bU[ks]));
  #pragma unroll
  for (int ks = 0; ks < 32; ++ks) asm volatile("" : "+v"(bV[ks]));

  const int nl    = wv * 4 + lk;              // local hidden unit this lane OWNS
  const int n_gl  = hgrp * 16 + nl;
  const int brow  = b0 + lc;
  const f32x4 bias4 = *(const f32x4*)(biasw + hgrp * 64 + nl * 4);
  const size_t HO = (size_t)B_SZ * T_SZ * H_SZ;
  const size_t CO = HO + (size_t)B_SZ * H_SZ;

  float cst = 0.f;   // c-state: one (batch, hidden) pair per lane

  // ---- prime x(0) into xlds[0] ----
  f32x4 xst[8];
  x_issue(x, b0, tid, 0, xst);
  asm volatile("s_waitcnt vmcnt(0)" ::: "memory");
  __builtin_amdgcn_sched_barrier(0);
  x_write(xlds, tid, xst);
  asm volatile("s_waitcnt lgkmcnt(0)" ::: "memory");
  __builtin_amdgcn_s_barrier();
  __builtin_amdgcn_sched_barrier(0);

#define HSTEP(ks, hv) { \
    acc[0] = __builtin_amdgcn_mfma_f32_16x16x32_f16(bV[0 * 8 + (ks)], hv, acc[0], 0, 0, 0); \
    acc[1] = __builtin_amdgcn_mfma_f32_16x16x32_f16(bV[1 * 8 + (ks)], hv, acc[1], 0, 0, 0); \
    acc[2] = __builtin_amdgcn_mfma_f32_16x16x32_f16(bV[2 * 8 + (ks)], hv, acc[2], 0, 0, 0); \
    acc[3] = __builtin_amdgcn_mfma_f32_16x16x32_f16(bV[3 * 8 + (ks)], hv, acc[3], 0, 0, 0); }

  for (int t = 0; t < T_SZ; ++t) {
    const _Float16* hcur  = hbuf + (size_t)(t & 1) * (B_SZ * H_SZ);
    _Float16*       hnext = hbuf + (size_t)((t + 1) & 1) * (B_SZ * H_SZ);
    char* xl_cur = xlds + (size_t)(t & 1) * 16384;
    char* xl_nxt = xlds + (size_t)((t + 1) & 1) * 16384;

    // ---- 1: issue x(t+1) prefetch (in flight across x-proj + poll) ----
    if (t + 1 < T_SZ) x_issue(x, b0, tid, t + 1, xst);

    f32x4 acc[4];
    acc[0] = f32x4{0.f, 0.f, 0.f, 0.f};
    acc[1] = f32x4{0.f, 0.f, 0.f, 0.f};
    acc[2] = f32x4{0.f, 0.f, 0.f, 0.f};
    acc[3] = f32x4{0.f, 0.f, 0.f, 0.f};

    // ---- 2: x projection, K-quarter: one shared x-frag feeds 4 col-tiles ----
    #pragma unroll
    for (int ks = 0; ks < 4; ++ks) {
      const f16x8 xa = *(const f16x8*)(xl_cur + (lc << 10) +
                                       ((wv * 256 + ks * 64 + lk * 16) ^ sw));
      acc[0] = __builtin_amdgcn_mfma_f32_16x16x32_f16(bU[0 * 4 + ks], xa, acc[0], 0, 0, 0);
      acc[1] = __builtin_amdgcn_mfma_f32_16x16x32_f16(bU[1 * 4 + ks], xa, acc[1], 0, 0, 0);
      acc[2] = __builtin_amdgcn_mfma_f32_16x16x32_f16(bU[2 * 4 + ks], xa, acc[2], 0, 0, 0);
      acc[3] = __builtin_amdgcn_mfma_f32_16x16x32_f16(bU[3 * 4 + ks], xa, acc[3], 0, 0, 0);
    }

    // ---- 3: wave0 polls all 64 producer flags ----
    if (t) {
      if (wv == 0) {
        const unsigned* fp = flags + lane;
        unsigned v;
        do {
          asm volatile("global_load_dword %0, %1, off sc0 sc1\n\ts_waitcnt vmcnt(0)"
                       : "=&v"(v) : "v"(fp) : "memory");
        } while (__any(v < (unsigned)t));
      }
      __builtin_amdgcn_s_barrier();
      __builtin_amdgcn_sched_barrier(0);
    }

    // ---- 4: drain x prefetch (uniform; wave0 already at 0) ----
    asm volatile("s_waitcnt vmcnt(0)" ::: "memory");
    __builtin_amdgcn_sched_barrier(0);

    // ---- 5: issue h fragment gather DIRECT to regs (this wave's K-quarter) ----
    f16x8 hv0, hv1, hv2, hv3, hv4, hv5, hv6, hv7;
    {
      const char* hp = (const char*)hcur + (size_t)brow * 2048 + wv * 512 + lk * 16;
      asm volatile("global_load_dwordx4 %0, %1, off sc0 sc1" : "=v"(hv0) : "v"(hp)        : "memory");
      asm volatile("global_load_dwordx4 %0, %1, off sc0 sc1" : "=v"(hv1) : "v"(hp + 64)   : "memory");
      asm volatile("global_load_dwordx4 %0, %1, off sc0 sc1" : "=v"(hv2) : "v"(hp + 128)  : "memory");
      asm volatile("global_load_dwordx4 %0, %1, off sc0 sc1" : "=v"(hv3) : "v"(hp + 192)  : "memory");
      asm volatile("global_load_dwordx4 %0, %1, off sc0 sc1" : "=v"(hv4) : "v"(hp + 256)  : "memory");
      asm volatile("global_load_dwordx4 %0, %1, off sc0 sc1" : "=v"(hv5) : "v"(hp + 320)  : "memory");
      asm volatile("global_load_dwordx4 %0, %1, off sc0 sc1" : "=v"(hv6) : "v"(hp + 384)  : "memory");
      asm volatile("global_load_dwordx4 %0, %1, off sc0 sc1" : "=v"(hv7) : "v"(hp + 448)  : "memory");
    }

    // ---- 6: stage x(t+1) to LDS (DS ops; doesn't perturb vmcnt staircase) ----
    if (t + 1 < T_SZ) x_write(xl_nxt, tid, xst);

    // ---- 7: h projection, vmcnt staircase (load return overlaps MFMA) ----
    asm volatile("s_waitcnt vmcnt(7)" ::: "memory"); __builtin_amdgcn_sched_barrier(0);
    HSTEP(0, hv0);
    asm volatile("s_waitcnt vmcnt(6)" ::: "memory"); __builtin_amdgcn_sched_barrier(0);
    HSTEP(1, hv1);
    asm volatile("s_waitcnt vmcnt(5)" ::: "memory"); __builtin_amdgcn_sched_barrier(0);
    HSTEP(2, hv2);
    asm volatile("s_waitcnt vmcnt(4)" ::: "memory"); __builtin_amdgcn_sched_barrier(0);
    HSTEP(3, hv3);
    asm volatile("s_waitcnt vmcnt(3)" ::: "memory"); __builtin_amdgcn_sched_barrier(0);
    HSTEP(4, hv4);
    asm volatile("s_waitcnt vmcnt(2)" ::: "memory"); __builtin_amdgcn_sched_barrier(0);
    HSTEP(5, hv5);
    asm volatile("s_waitcnt vmcnt(1)" ::: "memory"); __builtin_amdgcn_sched_barrier(0);
    HSTEP(6, hv6);
    asm volatile("s_waitcnt vmcnt(0)" ::: "memory"); __builtin_amdgcn_sched_barrier(0);
    HSTEP(7, hv7);

    // ---- 8: write K-partials; barrier ----
    #pragma unroll
    for (int ct = 0; ct < 4; ++ct)
      *(f32x4*)&pbuf[wv][lc][ct * 16 + lk * 4] = acc[ct];
    asm volatile("s_waitcnt lgkmcnt(0)" ::: "memory");
    __builtin_amdgcn_s_barrier();
    __builtin_amdgcn_sched_barrier(0);

    // ---- 9: owner reduce (4 partials + bias) -> gates, zero shuffles ----
    f32x4 s = bias4;
    #pragma unroll
    for (int w = 0; w < 4; ++w) {
      const f32x4 pv = *(const f32x4*)&pbuf[w][lc][nl * 4];
      s.x += pv.x; s.y += pv.y; s.z += pv.z; s.w += pv.w;
    }
    const float gi = 1.f / (1.f + __expf(-s.x));
    const float gf = 1.f / (1.f + __expf(-s.y));
    const float sg = 1.f / (1.f + __expf(-2.f * s.z));
    const float gg = 2.f * sg - 1.f;                    // tanh
    const float go = 1.f / (1.f + __expf(-s.w));
    const float cn = gf * cst + gi * gg;
    const float sc2 = 1.f / (1.f + __expf(-2.f * cn));
    const float hn = go * (2.f * sc2 - 1.f);
    cst = cn;

    // ---- 10: publish h (LLC, 2B/lane), drain, barrier, flag ----
    if (t < T_SZ - 1) {
      const unsigned short hv16 = f2h(hn);
      _Float16* hp2 = hnext + (size_t)brow * H_SZ + n_gl;
      asm volatile("global_store_short %0, %1, off sc0 sc1" :: "v"(hp2), "v"(hv16) : "memory");
    }
    asm volatile("s_waitcnt vmcnt(0)" ::: "memory");
    __builtin_amdgcn_s_barrier();
    if (t < T_SZ - 1 && tid == 64) {
      const unsigned* fp = flags + hgrp;
      unsigned tv = (unsigned)(t + 1);
      asm volatile("global_store_dword %0, %1, off sc0 sc1" :: "v"(fp), "v"(tv) : "memory");
    }

    // ---- 11: hidden_seq store (plain, off the critical path) ----
    out[(size_t)brow * (T_SZ * H_SZ) + (size_t)t * H_SZ + n_gl] = hn;
    if (t == T_SZ - 1) {
      out[HO + (size_t)brow * H_SZ + n_gl] = hn;
      out[CO + (size_t)brow * H_SZ + n_gl] = cn;
    }
  }
#undef HSTEP
}

extern "C" void kernel_launch(void* const* d_in, const int* in_sizes, int n_in,
                              void* d_out, int out_size, void* d_ws, size_t ws_size,
                              hipStream_t stream) {
  const float* x = (const float*)d_in[0];
  const float* U[4]  = {(const float*)d_in[1], (const float*)d_in[4],
                        (const float*)d_in[7], (const float*)d_in[10]};
  const float* V[4]  = {(const float*)d_in[2], (const float*)d_in[5],
                        (const float*)d_in[8], (const float*)d_in[11]};
  const float* bb[4] = {(const float*)d_in[3], (const float*)d_in[6],
                        (const float*)d_in[9], (const float*)d_in[12]};
  float* out = (float*)d_out;

  char* p = (char*)d_ws;
  _Float16* Ubt = (_Float16*)p; p += (size_t)G4 * I_SZ * 2;          // 4 MB
  _Float16* Vt  = (_Float16*)p; p += (size_t)G4 * H_SZ * 2;          // 8 MB
  float*    biasw = (float*)p;  p += (size_t)G4 * 4;                 // 16 KB
  _Float16* hbuf  = (_Float16*)p; p += (size_t)2 * B_SZ * H_SZ * 2;  // 256 KB
  unsigned* bar   = (unsigned*)p;                                    // 16 KB

  for (int qq = 0; qq < 4; ++qq)
    hipLaunchKernelGGL(trans_kernel, dim3(16, 8), dim3(256), 0, stream, U[qq], Ubt, I_SZ, qq);
  for (int qq = 0; qq < 4; ++qq)
    hipLaunchKernelGGL(trans_kernel, dim3(16, 16), dim3(256), 0, stream, V[qq], Vt, H_SZ, qq);
  hipLaunchKernelGGL(bias_kernel, dim3(16), dim3(256), 0, stream, bb[0], bb[1], bb[2], bb[3], biasw);

  // h(0) = 0 (buffer 0 read at t=0); flags = 0 (graph-replay safe)
  hipMemsetAsync(hbuf, 0, (size_t)B_SZ * H_SZ * 2, stream);
  hipMemsetAsync(bar, 0, 16384, stream);

  hipLaunchKernelGGL(lstm_recur, dim3(NBLK), dim3(256), 0, stream,
                     x, Ubt, Vt, biasw, out, hbuf, bar);
}